// Round 1
// baseline (1347.924 us; speedup 1.0000x reference)
//
#include <hip/hip_runtime.h>
#include <math.h>

#define HW 36864
#define CD 192
#define NH 6
#define HDIM 32
#define HIDD 768

__device__ __forceinline__ float gelu_f(float x) {
  return 0.5f * x * (1.0f + erff(x * 0.70710678118654752f));
}

// ---------------- LayerNorm (channel-major in/out), thread per token ----------------
__global__ __launch_bounds__(256)
void ln_kernel(const float* __restrict__ in, const float* __restrict__ g,
               const float* __restrict__ b, float* __restrict__ out)
{
  const int p = blockIdx.x * 256 + threadIdx.x;
  float s = 0.f, sq = 0.f;
  for (int c = 0; c < CD; ++c) {
    float v = in[(size_t)c * HW + p];
    s += v; sq += v * v;
  }
  const float m = s * (1.0f / CD);
  float var = sq * (1.0f / CD) - m * m;
  var = fmaxf(var, 0.f);
  const float r = rsqrtf(var + 1e-5f);
  for (int c = 0; c < CD; ++c) {
    float v = in[(size_t)c * HW + p];
    out[(size_t)c * HW + p] = (v - m) * r * g[c] + b[c];
  }
}

// ---------------- fp32 GEMM: out[m][n] = A[m][:] . B[:][n] (+ epilogue) ----------------
// MODE 0: QKV   — A channel-major, 3 B-segments, +bias, store channel-major
// MODE 1: PROJ  — A token-major (ld=K), +bias +aux(channel-major), store channel-major
// MODE 2: FC1   — A channel-major, +bias, GELU, store channel-major
// MODE 3: FC2   — A channel-major, +bias +aux(channel-major), store token-major (CD cols)
// BM=128, BN=64, BK=16, 128 threads, 8x8 register tile.
template<int MODE>
__global__ __launch_bounds__(128)
void gemm_kernel(const float* __restrict__ A,
                 const float* __restrict__ B0, const float* __restrict__ B1, const float* __restrict__ B2,
                 const float* __restrict__ bias0, const float* __restrict__ bias1, const float* __restrict__ bias2,
                 const float* __restrict__ aux, float* __restrict__ out,
                 int K, int ldB)
{
  constexpr bool A_CM = (MODE != 1);
  const int n0 = blockIdx.x * 64;
  const int m0 = blockIdx.y * 128;
  const int seg = n0 / ldB;
  const float* Bp    = (seg == 0) ? B0 : (seg == 1 ? B1 : B2);
  const float* biasp = (seg == 0) ? bias0 : (seg == 1 ? bias1 : bias2);
  const int jl0 = n0 - seg * ldB;

  alignas(16) __shared__ float As[16][132];
  alignas(16) __shared__ float Bs[16][68];

  const int tid = threadIdx.x;
  const int jg = tid & 7;        // 0..7  -> 8 cols
  const int ig = tid >> 3;       // 0..15 -> 8 rows

  float acc[8][8];
  #pragma unroll
  for (int a = 0; a < 8; ++a)
    #pragma unroll
    for (int b = 0; b < 8; ++b) acc[a][b] = 0.f;

  for (int k0 = 0; k0 < K; k0 += 16) {
    if (A_CM) {
      #pragma unroll
      for (int r = 0; r < 4; ++r) {
        int i2 = tid + r * 128;
        int c = i2 >> 5, m4 = (i2 & 31) << 2;
        const float4 va = *(const float4*)(A + (size_t)(k0 + c) * HW + m0 + m4);
        *(float4*)&As[c][m4] = va;
      }
    } else {
      #pragma unroll
      for (int r = 0; r < 4; ++r) {
        int i2 = tid + r * 128;
        int m = i2 >> 2, c4 = (i2 & 3) << 2;
        const float4 va = *(const float4*)(A + (size_t)(m0 + m) * K + k0 + c4);
        As[c4 + 0][m] = va.x; As[c4 + 1][m] = va.y;
        As[c4 + 2][m] = va.z; As[c4 + 3][m] = va.w;
      }
    }
    #pragma unroll
    for (int r = 0; r < 2; ++r) {
      int i2 = tid + r * 128;
      int c = i2 >> 4, j4 = (i2 & 15) << 2;
      *(float4*)&Bs[c][j4] = *(const float4*)(Bp + (size_t)(k0 + c) * ldB + jl0 + j4);
    }
    __syncthreads();
    #pragma unroll
    for (int k = 0; k < 16; ++k) {
      float af[8], bf[8];
      *(float4*)&af[0] = *(float4*)&As[k][ig * 8];
      *(float4*)&af[4] = *(float4*)&As[k][ig * 8 + 4];
      *(float4*)&bf[0] = *(float4*)&Bs[k][jg * 8];
      *(float4*)&bf[4] = *(float4*)&Bs[k][jg * 8 + 4];
      #pragma unroll
      for (int x = 0; x < 8; ++x)
        #pragma unroll
        for (int y = 0; y < 8; ++y)
          acc[x][y] = fmaf(af[x], bf[y], acc[x][y]);
    }
    __syncthreads();
  }

  float bv[8];
  #pragma unroll
  for (int j = 0; j < 8; ++j) bv[j] = biasp[jl0 + jg * 8 + j];

  if (MODE == 0 || MODE == 1 || MODE == 2) {
    #pragma unroll
    for (int j = 0; j < 8; ++j) {
      const int n = n0 + jg * 8 + j;
      const size_t ob = (size_t)n * HW + m0 + ig * 8;
      float o[8];
      #pragma unroll
      for (int i3 = 0; i3 < 8; ++i3) o[i3] = acc[i3][j] + bv[j];
      if (MODE == 1) {
        const float4 x1 = *(const float4*)(aux + ob);
        const float4 x2 = *(const float4*)(aux + ob + 4);
        o[0] += x1.x; o[1] += x1.y; o[2] += x1.z; o[3] += x1.w;
        o[4] += x2.x; o[5] += x2.y; o[6] += x2.z; o[7] += x2.w;
      }
      if (MODE == 2) {
        #pragma unroll
        for (int i3 = 0; i3 < 8; ++i3) o[i3] = gelu_f(o[i3]);
      }
      *(float4*)(out + ob)     = make_float4(o[0], o[1], o[2], o[3]);
      *(float4*)(out + ob + 4) = make_float4(o[4], o[5], o[6], o[7]);
    }
  } else {
    #pragma unroll
    for (int i3 = 0; i3 < 8; ++i3) {
      const int m = m0 + ig * 8 + i3;
      float o[8];
      #pragma unroll
      for (int j = 0; j < 8; ++j)
        o[j] = acc[i3][j] + bv[j] + aux[(size_t)(n0 + jg * 8 + j) * HW + m];
      *(float4*)(out + (size_t)m * CD + n0 + jg * 8)     = make_float4(o[0], o[1], o[2], o[3]);
      *(float4*)(out + (size_t)m * CD + n0 + jg * 8 + 4) = make_float4(o[4], o[5], o[6], o[7]);
    }
  }
}

// ---------------- depthwise 5x5 conv + bias + exact GELU (+optional residual add) ----------------
template<bool ADD>
__global__ __launch_bounds__(256)
void dwconv_kernel(const float* __restrict__ in, const float* __restrict__ w,
                   const float* __restrict__ bias, float* __restrict__ out)
{
  const int plane = blockIdx.z;
  const int bx = blockIdx.x * 64, by = blockIdx.y * 4;
  __shared__ float tile[8][68];
  __shared__ float ws[26];
  const int tid = threadIdx.x;
  if (tid < 26) ws[tid] = (tid < 25) ? w[plane * 25 + tid] : bias[plane];
  const float* ip = in + (size_t)plane * HW;
  for (int e = tid; e < 544; e += 256) {
    int r = e / 68, cc = e - r * 68;
    int gy = by + r - 2, gx = bx + cc - 2;
    tile[r][cc] = (gy >= 0 && gy < 192 && gx >= 0 && gx < 192) ? ip[gy * 192 + gx] : 0.f;
  }
  __syncthreads();
  const int tx = tid & 63, ty = tid >> 6;
  float acc = 0.f;
  #pragma unroll
  for (int dy = 0; dy < 5; ++dy)
    #pragma unroll
    for (int dx = 0; dx < 5; ++dx)
      acc = fmaf(tile[ty + dy][tx + dx], ws[dy * 5 + dx], acc);
  float v = gelu_f(acc + ws[25]);
  if (ADD) v += tile[ty + 2][tx + 2];
  out[(size_t)plane * HW + (by + ty) * 192 + bx + tx] = v;
}

// ---------------- fused window attention (one block per window-head) ----------------
// dense fp32 scores -> gather(+rpb) -> softmax -> *pfa -> renorm -> exact top-64
// (radix-select on float bits, ties by lowest index) -> sparse AmV -> +vLePE
// -> store token-major (window reverse fused).
__global__ __launch_bounds__(512)
void attn_kernel(const float* __restrict__ qg, const float* __restrict__ kg,
                 const float* __restrict__ vg, const float* __restrict__ vlg,
                 const float* __restrict__ pfa_v, const int* __restrict__ pfa_i,
                 const int* __restrict__ rpi, const float* __restrict__ rpb_t,
                 float* __restrict__ attn_out)
{
  const int h = blockIdx.x;       // head
  const int win = blockIdx.y;     // window
  const int wy = (win / 12) * 16;
  const int wx = (win - (win / 12) * 12) * 16;
  const size_t hb = (size_t)h * HDIM * HW;

  alignas(16) __shared__ float kT[32][260];   // [d][j], f4-row reads
  __shared__ float vT[32][257];               // [d][j], column b32 reads (conflict-free)
  alignas(16) __shared__ float Sb[64][260];   // score tile
  alignas(16) __shared__ float qTt[32][68];   // q tile [d][i]
  __shared__ float rpb_h[961];
  __shared__ float2 selbuf[8][64];            // per-wave selected (val, j-bits)

  const int tid = threadIdx.x;
  const int lane = tid & 63, wave = tid >> 6;

  for (int r = tid; r < 961; r += 512) rpb_h[r] = rpb_t[r * 6 + h];

  #pragma unroll
  for (int j0 = 0; j0 < 256; j0 += 64) {
    int j = j0 + lane;
    int pg = (wy + (j >> 4)) * 192 + (wx + (j & 15));
    #pragma unroll
    for (int dd = 0; dd < 32; dd += 8) {
      int d = dd + wave;
      kT[d][j] = kg[hb + (size_t)d * HW + pg];
      vT[d][j] = vg[hb + (size_t)d * HW + pg];
    }
  }
  __syncthreads();

  const float scale = 0.17677669529663689f;   // 32^-0.5
  const size_t wb = ((size_t)win * NH + h) * 256;

  for (int tt = 0; tt < 4; ++tt) {
    // ---- load q tile (scaled) ----
    {
      int i = tt * 64 + lane;
      int pg = (wy + (i >> 4)) * 192 + (wx + (i & 15));
      #pragma unroll
      for (int dd = 0; dd < 32; dd += 8) {
        int d = dd + wave;
        qTt[d][lane] = qg[hb + (size_t)d * HW + pg] * scale;
      }
    }
    __syncthreads();
    // ---- dense scores: Sb[iq][j] = sum_d qTt[d][iq]*kT[d][j] ----
    {
      const int jbase = (tid & 63) * 4;   // 0..252
      const int ibase = wave * 8;         // 0..56
      float acc[8][4];
      #pragma unroll
      for (int a = 0; a < 8; ++a)
        #pragma unroll
        for (int b = 0; b < 4; ++b) acc[a][b] = 0.f;
      #pragma unroll
      for (int d = 0; d < 32; ++d) {
        float af[8], bf[4];
        *(float4*)&af[0] = *(const float4*)&qTt[d][ibase];
        *(float4*)&af[4] = *(const float4*)&qTt[d][ibase + 4];
        *(float4*)&bf[0] = *(const float4*)&kT[d][jbase];
        #pragma unroll
        for (int x = 0; x < 8; ++x)
          #pragma unroll
          for (int y = 0; y < 4; ++y)
            acc[x][y] = fmaf(af[x], bf[y], acc[x][y]);
      }
      #pragma unroll
      for (int x = 0; x < 8; ++x)
        *(float4*)&Sb[ibase + x][jbase] = make_float4(acc[x][0], acc[x][1], acc[x][2], acc[x][3]);
    }
    __syncthreads();
    // ---- per-query: gather + softmax + pfa renorm + top-64 + AmV ----
    int pj1[8], pj2[8]; float ppv1[8], ppv2[8];
    #pragma unroll
    for (int u = 0; u < 8; ++u) {
      const int iq = u * 8 + wave;
      const size_t base = (wb + (size_t)(tt * 64 + iq)) * 128;
      pj1[u]  = pfa_i[base + lane];
      pj2[u]  = pfa_i[base + 64 + lane];
      ppv1[u] = pfa_v[base + lane];
      ppv2[u] = pfa_v[base + 64 + lane];
    }
    #pragma unroll
    for (int u = 0; u < 8; ++u) {
      const int iq = u * 8 + wave;       // row in Sb
      const int i  = tt * 64 + iq;       // query in window
      const int j1 = pj1[u], j2 = pj2[u];
      float s1 = Sb[iq][j1] + rpb_h[rpi[i * 256 + j1]];
      float s2 = Sb[iq][j2] + rpb_h[rpi[i * 256 + j2]];
      float mx = fmaxf(s1, s2);
      #pragma unroll
      for (int o = 32; o > 0; o >>= 1) mx = fmaxf(mx, __shfl_xor(mx, o));
      float e1 = expf(s1 - mx), e2 = expf(s2 - mx);
      float sm = e1 + e2;
      #pragma unroll
      for (int o = 32; o > 0; o >>= 1) sm += __shfl_xor(sm, o);
      const float rs = 1.0f / sm;
      float a1 = e1 * rs * ppv1[u];
      float a2 = e2 * rs * ppv2[u];
      float ts = a1 + a2;
      #pragma unroll
      for (int o = 32; o > 0; o >>= 1) ts += __shfl_xor(ts, o);
      const float rden = 1.0f / (ts + 1e-10f);
      a1 = (a1 + 1e-10f) * rden;         // uniform positive scale: ordering == reference
      a2 = (a2 + 1e-10f) * rden;
      // exact 64th-largest via radix select on positive-float bits
      const unsigned ub1 = __float_as_uint(a1), ub2 = __float_as_uint(a2);
      unsigned thr = 0u;
      for (int bit = 30; bit >= 0; --bit) {
        unsigned cand = thr | (1u << bit);
        int cnt = (int)__popcll(__ballot(ub1 >= cand)) + (int)__popcll(__ballot(ub2 >= cand));
        if (cnt >= 64) thr = cand;
      }
      const unsigned long long lmlt = (1ull << lane) - 1ull;
      const bool gt1 = ub1 > thr, gt2 = ub2 > thr;
      const bool eq1 = ub1 == thr, eq2 = ub2 == thr;
      const unsigned long long meq1 = __ballot(eq1), meq2 = __ballot(eq2);
      const int need = 64 - (int)__popcll(__ballot(gt1)) - (int)__popcll(__ballot(gt2));
      const bool sel1 = gt1 || (eq1 && (int)__popcll(meq1 & lmlt) < need);
      const bool sel2 = gt2 || (eq2 && ((int)__popcll(meq1) + (int)__popcll(meq2 & lmlt)) < need);
      const unsigned long long ms1 = __ballot(sel1), ms2 = __ballot(sel2);
      const int pos1 = (int)__popcll(ms1 & lmlt);
      const int pos2 = (int)__popcll(ms1) + (int)__popcll(ms2 & lmlt);
      if (sel1) selbuf[wave][pos1] = make_float2(a1, __int_as_float(j1));
      if (sel2) selbuf[wave][pos2] = make_float2(a2, __int_as_float(j2));
      // sparse AmV: out[i][d] = sum_s val_s * v[j_s][d]
      const int d = lane & 31, half = lane >> 5;
      float acc = 0.f;
      #pragma unroll
      for (int s = 0; s < 32; ++s) {
        float2 sv = selbuf[wave][half * 32 + s];
        acc = fmaf(sv.x, vT[d][__float_as_int(sv.y)], acc);
      }
      acc += __shfl_xor(acc, 32);
      const int pg = (wy + (i >> 4)) * 192 + (wx + (i & 15));
      if (lane < 32) {
        float o = acc + vlg[hb + (size_t)d * HW + pg];
        attn_out[(size_t)pg * CD + h * HDIM + d] = o;  // token-major, window-reversed
      }
    }
    __syncthreads();
  }
}

// ---------------- launch ----------------
extern "C" void kernel_launch(void* const* d_in, const int* in_sizes, int n_in,
                              void* d_out, int out_size, void* d_ws, size_t ws_size,
                              hipStream_t stream)
{
  (void)in_sizes; (void)n_in; (void)out_size; (void)ws_size;
  const float* features = (const float*)d_in[0];
  const float* pfa_v    = (const float*)d_in[1];
  const int*   pfa_i    = (const int*)d_in[2];
  const int*   rpi      = (const int*)d_in[3];
  const float* ln1_g    = (const float*)d_in[4];
  const float* ln1_b    = (const float*)d_in[5];
  const float* Wq_w     = (const float*)d_in[6];
  const float* Wq_b     = (const float*)d_in[7];
  const float* Wk_w     = (const float*)d_in[8];
  const float* Wk_b     = (const float*)d_in[9];
  const float* Wv_w     = (const float*)d_in[10];
  const float* Wv_b     = (const float*)d_in[11];
  const float* lepe_w   = (const float*)d_in[12];
  const float* lepe_b   = (const float*)d_in[13];
  const float* rpb_t    = (const float*)d_in[14];
  const float* proj_w   = (const float*)d_in[15];
  const float* proj_b   = (const float*)d_in[16];
  const float* ln2_g    = (const float*)d_in[17];
  const float* ln2_b    = (const float*)d_in[18];
  const float* fc1_w    = (const float*)d_in[19];
  const float* fc1_b    = (const float*)d_in[20];
  const float* dw_w     = (const float*)d_in[21];
  const float* dw_b     = (const float*)d_in[22];
  const float* fc2_w    = (const float*)d_in[23];
  const float* fc2_b    = (const float*)d_in[24];

  float* ws = (float*)d_ws;
  const size_t S = (size_t)HW * CD;
  float* x2     = ws;            // [0S,1S) alive to the end
  float* xn2    = ws + S;        // [1S,2S)
  float* xn     = ws + 2 * S;    // [2S,3S) dead after QKV
  float* qkv    = ws + 3 * S;    // [3S,6S) dead after attn
  float* q_ = qkv; float* k_ = qkv + S; float* v_ = qkv + 2 * S;
  float* vl_    = ws + 6 * S;    // [6S,7S) dead after attn
  float* attn_o = ws + 7 * S;    // [7S,8S) dead after proj
  float* y_     = ws + 2 * S;    // [2S,6S) reuse (xn/qkv dead)
  float* y2_    = ws + 6 * S;    // [6S,10S) reuse (vl/attn_o dead)
  float* out = (float*)d_out;

  // 1) LN1
  ln_kernel<<<dim3(HW / 256), 256, 0, stream>>>(features, ln1_g, ln1_b, xn);
  // 2) fused QKV projection (N=576, 3 segments)
  gemm_kernel<0><<<dim3(9, 288), 128, 0, stream>>>(xn, Wq_w, Wk_w, Wv_w, Wq_b, Wk_b, Wv_b,
                                                   nullptr, qkv, 192, 192);
  // 3) LePE: vl = gelu(dwconv5x5(v)+b)
  dwconv_kernel<false><<<dim3(3, 48, 192), 256, 0, stream>>>(v_, lepe_w, lepe_b, vl_);
  // 4) window attention (scores, softmax, pfa renorm, top-64, AmV, +vl)
  attn_kernel<<<dim3(6, 144), 512, 0, stream>>>(q_, k_, v_, vl_, pfa_v, pfa_i, rpi, rpb_t, attn_o);
  // 5) proj + shortcut -> x2 (channel-major)
  gemm_kernel<1><<<dim3(3, 288), 128, 0, stream>>>(attn_o, proj_w, proj_w, proj_w,
                                                   proj_b, proj_b, proj_b, features, x2, 192, 192);
  // 6) LN2
  ln_kernel<<<dim3(HW / 256), 256, 0, stream>>>(x2, ln2_g, ln2_b, xn2);
  // 7) fc1 + GELU -> y (channel-major, HIDx HW)
  gemm_kernel<2><<<dim3(12, 288), 128, 0, stream>>>(xn2, fc1_w, fc1_w, fc1_w,
                                                    fc1_b, fc1_b, fc1_b, nullptr, y_, 192, 768);
  // 8) y2 = y + gelu(dwconv5x5(y)+b)
  dwconv_kernel<true><<<dim3(3, 48, 768), 256, 0, stream>>>(y_, dw_w, dw_b, y2_);
  // 9) out = x2 + y2 @ fc2 + b  (token-major final output)
  gemm_kernel<3><<<dim3(3, 288), 128, 0, stream>>>(y2_, fc2_w, fc2_w, fc2_w,
                                                   fc2_b, fc2_b, fc2_b, x2, out, 768, 192);
}

// Round 2
// 939.983 us; speedup vs baseline: 1.4340x; 1.4340x over previous
//
#include <hip/hip_runtime.h>
#include <math.h>

#define HW 36864
#define CD 192
#define NH 6
#define HDIM 32
#define HIDD 768

typedef __attribute__((ext_vector_type(8))) short bf16x8;
typedef __attribute__((ext_vector_type(4))) float f32x4;

__device__ __forceinline__ float gelu_f(float x) {
  return 0.5f * x * (1.0f + erff(x * 0.70710678118654752f));
}
__device__ __forceinline__ unsigned short f2b(float f) {
  union { float f; unsigned u; } v; v.f = f;
  unsigned r = v.u + 0x7fff + ((v.u >> 16) & 1);   // RNE
  return (unsigned short)(r >> 16);
}
__device__ __forceinline__ float b2f(unsigned short b) {
  union { unsigned u; float f; } v; v.u = ((unsigned)b) << 16;
  return v.f;
}
__device__ __forceinline__ float ldv(const float* p) { return *p; }
__device__ __forceinline__ float ldv(const unsigned short* p) { return b2f(*p); }

// ---------------- LayerNorm: fp32 CM in -> bf16 CM out, thread per token ----------------
__global__ __launch_bounds__(256)
void ln_kernel(const float* __restrict__ in, const float* __restrict__ g,
               const float* __restrict__ b, unsigned short* __restrict__ out)
{
  const int p = blockIdx.x * 256 + threadIdx.x;
  float s = 0.f, sq = 0.f;
  for (int c = 0; c < CD; ++c) {
    float v = in[(size_t)c * HW + p];
    s += v; sq += v * v;
  }
  const float m = s * (1.0f / CD);
  float var = sq * (1.0f / CD) - m * m;
  var = fmaxf(var, 0.f);
  const float r = rsqrtf(var + 1e-5f);
  for (int c = 0; c < CD; ++c) {
    float v = in[(size_t)c * HW + p];
    out[(size_t)c * HW + p] = f2b((v - m) * r * g[c] + b[c]);
  }
}

// ---------------- bf16 CM [C][HW] -> bf16 TM [HW][C] transpose ----------------
__global__ __launch_bounds__(256)
void trans_kernel(const unsigned short* __restrict__ in, unsigned short* __restrict__ out, int C)
{
  __shared__ unsigned short ls[64][34];
  const int m0 = blockIdx.x * 64, c0 = blockIdx.y * 32;
  const int t = threadIdx.x;
  #pragma unroll
  for (int r = 0; r < 4; ++r) {
    int idx = t + r * 256;                       // 1024 dwords = 32c x 64m
    int c = idx >> 5, dm = idx & 31;
    unsigned d = *(const unsigned*)(in + (size_t)(c0 + c) * HW + m0 + dm * 2);
    ls[dm * 2][c] = (unsigned short)d;
    ls[dm * 2 + 1][c] = (unsigned short)(d >> 16);
  }
  __syncthreads();
  #pragma unroll
  for (int r = 0; r < 4; ++r) {
    int idx = t + r * 256;                       // 64m x 16 dwords
    int m = idx >> 4, dc = idx & 15;
    unsigned d = (unsigned)ls[m][dc * 2] | ((unsigned)ls[m][dc * 2 + 1] << 16);
    *(unsigned*)(out + (size_t)(m0 + m) * C + c0 + dc * 2) = d;
  }
}

// ---------------- weight prep: fp32 [K][N] -> bf16 [N][K] ----------------
__global__ __launch_bounds__(256)
void wtrans_kernel(const float* __restrict__ in, unsigned short* __restrict__ out, int K, int N)
{
  __shared__ float ls[32][33];
  const int k0 = blockIdx.x * 32, n0 = blockIdx.y * 32;
  const int t = threadIdx.x;
  #pragma unroll
  for (int r = 0; r < 4; ++r) {
    int idx = t + r * 256;
    int k = idx >> 5, n = idx & 31;
    ls[k][n] = in[(size_t)(k0 + k) * N + n0 + n];
  }
  __syncthreads();
  #pragma unroll
  for (int r = 0; r < 4; ++r) {
    int idx = t + r * 256;
    int n = idx >> 5, k = idx & 31;
    out[(size_t)(n0 + n) * K + k0 + k] = f2b(ls[k][n]);
  }
}

// ---------------- bf16 MFMA GEMM: D[m][n] = A[m][:].Wt[n][:] + epilogue ----------------
// A: [M][K] bf16 token-major. Wt: [N][K] bf16. BM=128 BN=64 BK=32, 256 thr, 4 waves 2x2.
// MODE 0: QKV (3 weight segments of 192) -> fp32 CM out, +bias
// MODE 1: PROJ -> fp32 CM out, +bias +aux (fp32 CM)
// MODE 2: FC1  -> bf16 CM out, +bias, GELU
// MODE 3: FC2  -> fp32 TM out, +bias +aux (fp32 CM)
template<int MODE>
__global__ __launch_bounds__(256, 4)
void mgemm_kernel(const unsigned short* __restrict__ A,
                  const unsigned short* __restrict__ W0, const unsigned short* __restrict__ W1,
                  const unsigned short* __restrict__ W2,
                  const float* __restrict__ b0, const float* __restrict__ b1, const float* __restrict__ b2,
                  const float* __restrict__ aux, void* __restrict__ outv,
                  int K, int segN)
{
  const int n0 = blockIdx.x * 64;
  const int m0 = blockIdx.y * 128;
  const int seg = n0 / segN;
  const unsigned short* Wp = (seg == 0) ? W0 : (seg == 1 ? W1 : W2);
  const float* biasp = (seg == 0) ? b0 : (seg == 1 ? b1 : b2);
  const int nl0 = n0 - seg * segN;

  __shared__ unsigned short As[128 * 32];   // [m][k], 8 KB
  __shared__ unsigned short Bs[64 * 32];    // [n][k], 4 KB

  const int tid = threadIdx.x;
  const int lane = tid & 63, wave = tid >> 6;
  const int wm = (wave >> 1) * 64, wn = (wave & 1) * 32;
  const int fm = lane & 15, fq = lane >> 4;
  const int ar = tid >> 2, akq = tid & 3;   // staging: row, k-quad

  f32x4 acc[4][2];
  #pragma unroll
  for (int i = 0; i < 4; ++i) { acc[i][0] = (f32x4)(0.f); acc[i][1] = (f32x4)(0.f); }

  uint4 rA0, rA1, rB, nA0, nA1, nB;
  rA0 = *(const uint4*)(A + (size_t)(m0 + ar) * K + akq * 8);
  rA1 = *(const uint4*)(A + (size_t)(m0 + ar + 64) * K + akq * 8);
  rB  = *(const uint4*)(Wp + (size_t)(nl0 + ar) * K + akq * 8);

  for (int k0 = 0; k0 < K; k0 += 32) {
    *(uint4*)(&As[ar * 32 + akq * 8]) = rA0;
    *(uint4*)(&As[(ar + 64) * 32 + akq * 8]) = rA1;
    *(uint4*)(&Bs[ar * 32 + akq * 8]) = rB;
    __syncthreads();
    const int kn = (k0 + 32 < K) ? k0 + 32 : k0;   // clamped prefetch
    nA0 = *(const uint4*)(A + (size_t)(m0 + ar) * K + kn + akq * 8);
    nA1 = *(const uint4*)(A + (size_t)(m0 + ar + 64) * K + kn + akq * 8);
    nB  = *(const uint4*)(Wp + (size_t)(nl0 + ar) * K + kn + akq * 8);
    bf16x8 af[4], bf[2];
    #pragma unroll
    for (int mt = 0; mt < 4; ++mt)
      af[mt] = *(const bf16x8*)(&As[(wm + mt * 16 + fm) * 32 + fq * 8]);
    #pragma unroll
    for (int nt = 0; nt < 2; ++nt)
      bf[nt] = *(const bf16x8*)(&Bs[(wn + nt * 16 + fm) * 32 + fq * 8]);
    #pragma unroll
    for (int mt = 0; mt < 4; ++mt)
      #pragma unroll
      for (int nt = 0; nt < 2; ++nt)
        acc[mt][nt] = __builtin_amdgcn_mfma_f32_16x16x32_bf16(af[mt], bf[nt], acc[mt][nt], 0, 0, 0);
    __syncthreads();
    rA0 = nA0; rA1 = nA1; rB = nB;
  }

  #pragma unroll
  for (int nt = 0; nt < 2; ++nt) {
    const int n = n0 + wn + nt * 16 + fm;
    const float bia = biasp[nl0 + wn + nt * 16 + fm];
    #pragma unroll
    for (int mt = 0; mt < 4; ++mt) {
      const int mb = m0 + wm + mt * 16 + fq * 4;
      float o[4];
      #pragma unroll
      for (int r = 0; r < 4; ++r) o[r] = acc[mt][nt][r] + bia;
      if (MODE == 0) {
        *(float4*)((float*)outv + (size_t)n * HW + mb) = make_float4(o[0], o[1], o[2], o[3]);
      } else if (MODE == 1) {
        const float4 ax = *(const float4*)(aux + (size_t)n * HW + mb);
        *(float4*)((float*)outv + (size_t)n * HW + mb) =
            make_float4(o[0] + ax.x, o[1] + ax.y, o[2] + ax.z, o[3] + ax.w);
      } else if (MODE == 2) {
        unsigned short h0 = f2b(gelu_f(o[0])), h1 = f2b(gelu_f(o[1]));
        unsigned short h2 = f2b(gelu_f(o[2])), h3 = f2b(gelu_f(o[3]));
        uint2 pk = make_uint2((unsigned)h0 | ((unsigned)h1 << 16),
                              (unsigned)h2 | ((unsigned)h3 << 16));
        *(uint2*)((unsigned short*)outv + (size_t)n * HW + mb) = pk;
      } else {
        const float4 ax = *(const float4*)(aux + (size_t)n * HW + mb);
        float* op = (float*)outv;
        op[(size_t)(mb + 0) * CD + n] = o[0] + ax.x;
        op[(size_t)(mb + 1) * CD + n] = o[1] + ax.y;
        op[(size_t)(mb + 2) * CD + n] = o[2] + ax.z;
        op[(size_t)(mb + 3) * CD + n] = o[3] + ax.w;
      }
    }
  }
}

// ---------------- depthwise 5x5 conv + bias + exact GELU (+optional residual) ----------------
template<typename TI, typename TO, bool ADD>
__global__ __launch_bounds__(256)
void dwconv_kernel(const TI* __restrict__ in, const float* __restrict__ w,
                   const float* __restrict__ bias, TO* __restrict__ out)
{
  const int plane = blockIdx.z;
  const int bx = blockIdx.x * 64, by = blockIdx.y * 4;
  __shared__ float tile[8][68];
  __shared__ float ws[26];
  const int tid = threadIdx.x;
  if (tid < 26) ws[tid] = (tid < 25) ? w[plane * 25 + tid] : bias[plane];
  const TI* ip = in + (size_t)plane * HW;
  for (int e = tid; e < 544; e += 256) {
    int r = e / 68, cc = e - r * 68;
    int gy = by + r - 2, gx = bx + cc - 2;
    tile[r][cc] = (gy >= 0 && gy < 192 && gx >= 0 && gx < 192) ? ldv(ip + gy * 192 + gx) : 0.f;
  }
  __syncthreads();
  const int tx = tid & 63, ty = tid >> 6;
  float acc = 0.f;
  #pragma unroll
  for (int dy = 0; dy < 5; ++dy)
    #pragma unroll
    for (int dx = 0; dx < 5; ++dx)
      acc = fmaf(tile[ty + dy][tx + dx], ws[dy * 5 + dx], acc);
  float v = gelu_f(acc + ws[25]);
  if (ADD) v += tile[ty + 2][tx + 2];
  float* outf = nullptr; (void)outf;
  if (sizeof(TO) == 4) ((float*)out)[(size_t)plane * HW + (by + ty) * 192 + bx + tx] = v;
  else ((unsigned short*)out)[(size_t)plane * HW + (by + ty) * 192 + bx + tx] = f2b(v);
}

// ---------------- fused window attention, 1024 threads (16 waves) per window-head ----------------
__global__ __launch_bounds__(1024, 4)
void attn_kernel(const float* __restrict__ qg, const float* __restrict__ kg,
                 const float* __restrict__ vg, const float* __restrict__ vlg,
                 const float* __restrict__ pfa_v, const int* __restrict__ pfa_i,
                 const int* __restrict__ rpi, const float* __restrict__ rpb_t,
                 unsigned short* __restrict__ attn_out)
{
  const int h = blockIdx.x;
  const int win = blockIdx.y;
  const int wy = (win / 12) * 16;
  const int wx = (win - (win / 12) * 12) * 16;
  const size_t hb = (size_t)h * HDIM * HW;

  alignas(16) __shared__ float kT[32][260];
  __shared__ float vT[32][257];
  alignas(16) __shared__ float Sb[64][260];
  alignas(16) __shared__ float qTt[32][68];
  __shared__ float rpb_h[961];
  __shared__ float2 selbuf[16][64];

  const int tid = threadIdx.x;
  const int lane = tid & 63, wave = tid >> 6;

  for (int r = tid; r < 961; r += 1024) rpb_h[r] = rpb_t[r * 6 + h];

  #pragma unroll
  for (int j0 = 0; j0 < 256; j0 += 64) {
    int j = j0 + lane;
    int pg = (wy + (j >> 4)) * 192 + (wx + (j & 15));
    #pragma unroll
    for (int dd = 0; dd < 32; dd += 16) {
      int d = dd + wave;
      kT[d][j] = kg[hb + (size_t)d * HW + pg];
      vT[d][j] = vg[hb + (size_t)d * HW + pg];
    }
  }
  __syncthreads();

  const float scale = 0.17677669529663689f;
  const size_t wb = ((size_t)win * NH + h) * 256;

  for (int tt = 0; tt < 4; ++tt) {
    {
      int i = tt * 64 + lane;
      int pg = (wy + (i >> 4)) * 192 + (wx + (i & 15));
      #pragma unroll
      for (int dd = 0; dd < 32; dd += 16) {
        int d = dd + wave;
        qTt[d][lane] = qg[hb + (size_t)d * HW + pg] * scale;
      }
    }
    __syncthreads();
    {
      const int jbase = lane * 4;       // 0..252
      const int ibase = wave * 4;       // 0..60
      float acc[4][4];
      #pragma unroll
      for (int a = 0; a < 4; ++a)
        #pragma unroll
        for (int b = 0; b < 4; ++b) acc[a][b] = 0.f;
      #pragma unroll
      for (int d = 0; d < 32; ++d) {
        float af[4], bf[4];
        *(float4*)&af[0] = *(const float4*)&qTt[d][ibase];
        *(float4*)&bf[0] = *(const float4*)&kT[d][jbase];
        #pragma unroll
        for (int x = 0; x < 4; ++x)
          #pragma unroll
          for (int y = 0; y < 4; ++y)
            acc[x][y] = fmaf(af[x], bf[y], acc[x][y]);
      }
      #pragma unroll
      for (int x = 0; x < 4; ++x)
        *(float4*)&Sb[ibase + x][jbase] = make_float4(acc[x][0], acc[x][1], acc[x][2], acc[x][3]);
    }
    __syncthreads();
    int pj1[4], pj2[4]; float ppv1[4], ppv2[4], rb1[4], rb2[4];
    #pragma unroll
    for (int u = 0; u < 4; ++u) {
      const int iq = u * 16 + wave;
      const int i = tt * 64 + iq;
      const size_t base = (wb + (size_t)i) * 128;
      pj1[u]  = pfa_i[base + lane];
      pj2[u]  = pfa_i[base + 64 + lane];
      ppv1[u] = pfa_v[base + lane];
      ppv2[u] = pfa_v[base + 64 + lane];
      rb1[u]  = rpb_h[rpi[i * 256 + pj1[u]]];
      rb2[u]  = rpb_h[rpi[i * 256 + pj2[u]]];
    }
    #pragma unroll
    for (int u = 0; u < 4; ++u) {
      const int iq = u * 16 + wave;
      const int i  = tt * 64 + iq;
      const int j1 = pj1[u], j2 = pj2[u];
      float s1 = Sb[iq][j1] + rb1[u];
      float s2 = Sb[iq][j2] + rb2[u];
      float mx = fmaxf(s1, s2);
      #pragma unroll
      for (int o = 32; o > 0; o >>= 1) mx = fmaxf(mx, __shfl_xor(mx, o));
      float e1 = expf(s1 - mx), e2 = expf(s2 - mx);
      float sm = e1 + e2;
      #pragma unroll
      for (int o = 32; o > 0; o >>= 1) sm += __shfl_xor(sm, o);
      const float rs = 1.0f / sm;
      float a1 = e1 * rs * ppv1[u];
      float a2 = e2 * rs * ppv2[u];
      float ts = a1 + a2;
      #pragma unroll
      for (int o = 32; o > 0; o >>= 1) ts += __shfl_xor(ts, o);
      const float rden = 1.0f / (ts + 1e-10f);
      a1 = (a1 + 1e-10f) * rden;
      a2 = (a2 + 1e-10f) * rden;
      const unsigned ub1 = __float_as_uint(a1), ub2 = __float_as_uint(a2);
      unsigned thr = 0u;
      for (int bit = 30; bit >= 0; --bit) {
        unsigned cand = thr | (1u << bit);
        int cnt = (int)__popcll(__ballot(ub1 >= cand)) + (int)__popcll(__ballot(ub2 >= cand));
        if (cnt >= 64) thr = cand;
      }
      const unsigned long long lmlt = (1ull << lane) - 1ull;
      const bool gt1 = ub1 > thr, gt2 = ub2 > thr;
      const bool eq1 = ub1 == thr, eq2 = ub2 == thr;
      const unsigned long long meq1 = __ballot(eq1), meq2 = __ballot(eq2);
      const int need = 64 - (int)__popcll(__ballot(gt1)) - (int)__popcll(__ballot(gt2));
      const bool sel1 = gt1 || (eq1 && (int)__popcll(meq1 & lmlt) < need);
      const bool sel2 = gt2 || (eq2 && ((int)__popcll(meq1) + (int)__popcll(meq2 & lmlt)) < need);
      const unsigned long long ms1 = __ballot(sel1), ms2 = __ballot(sel2);
      const int pos1 = (int)__popcll(ms1 & lmlt);
      const int pos2 = (int)__popcll(ms1) + (int)__popcll(ms2 & lmlt);
      if (sel1) selbuf[wave][pos1] = make_float2(a1, __int_as_float(j1));
      if (sel2) selbuf[wave][pos2] = make_float2(a2, __int_as_float(j2));
      const int d = lane & 31, half = lane >> 5;
      float acc = 0.f;
      #pragma unroll
      for (int s = 0; s < 32; ++s) {
        float2 sv = selbuf[wave][half * 32 + s];
        acc = fmaf(sv.x, vT[d][__float_as_int(sv.y)], acc);
      }
      acc += __shfl_xor(acc, 32);
      const int pg = (wy + (i >> 4)) * 192 + (wx + (i & 15));
      if (lane < 32) {
        float o = acc + vlg[hb + (size_t)d * HW + pg];
        attn_out[(size_t)pg * CD + h * HDIM + d] = f2b(o);   // bf16 token-major
      }
    }
    __syncthreads();
  }
}

// ---------------- launch ----------------
extern "C" void kernel_launch(void* const* d_in, const int* in_sizes, int n_in,
                              void* d_out, int out_size, void* d_ws, size_t ws_size,
                              hipStream_t stream)
{
  (void)in_sizes; (void)n_in; (void)out_size; (void)ws_size;
  const float* features = (const float*)d_in[0];
  const float* pfa_v    = (const float*)d_in[1];
  const int*   pfa_i    = (const int*)d_in[2];
  const int*   rpi      = (const int*)d_in[3];
  const float* ln1_g    = (const float*)d_in[4];
  const float* ln1_b    = (const float*)d_in[5];
  const float* Wq_w     = (const float*)d_in[6];
  const float* Wq_b     = (const float*)d_in[7];
  const float* Wk_w     = (const float*)d_in[8];
  const float* Wk_b     = (const float*)d_in[9];
  const float* Wv_w     = (const float*)d_in[10];
  const float* Wv_b     = (const float*)d_in[11];
  const float* lepe_w   = (const float*)d_in[12];
  const float* lepe_b   = (const float*)d_in[13];
  const float* rpb_t    = (const float*)d_in[14];
  const float* proj_w   = (const float*)d_in[15];
  const float* proj_b   = (const float*)d_in[16];
  const float* ln2_g    = (const float*)d_in[17];
  const float* ln2_b    = (const float*)d_in[18];
  const float* fc1_w    = (const float*)d_in[19];
  const float* fc1_b    = (const float*)d_in[20];
  const float* dw_w     = (const float*)d_in[21];
  const float* dw_b     = (const float*)d_in[22];
  const float* fc2_w    = (const float*)d_in[23];
  const float* fc2_b    = (const float*)d_in[24];

  char* ws = (char*)d_ws;
  const size_t S  = (size_t)HW * CD;        // elems
  const size_t SB = S * 4;                  // bytes (28.3 MB)
  // arena (peak ~199 MB; R1 proved >=283 MB available)
  float* qkv   = (float*)(ws);                               // [0,3SB) steps QKV..attn
  float* q_ = qkv; float* k_ = qkv + S; float* v_ = qkv + 2 * S;
  float* vl    = (float*)(ws + 3 * SB);                      // [3SB,4SB)
  unsigned short* xnb    = (unsigned short*)(ws + 4 * SB);             // bf16 CM
  unsigned short* xnt    = (unsigned short*)(ws + 4 * SB + SB / 2);    // bf16 TM
  unsigned short* attn_o = (unsigned short*)(ws + 4 * SB);             // reuse xnb
  float* x2    = (float*)(ws + 5 * SB);                      // [5SB,6SB) live to end
  unsigned short* xn2b   = (unsigned short*)(ws + 6 * SB);
  unsigned short* xn2t   = (unsigned short*)(ws + 6 * SB + SB / 2);
  unsigned short* y_     = (unsigned short*)(ws);            // [0,2SB) bf16 CM 768xHW (qkv dead)
  unsigned short* y2_    = (unsigned short*)(ws + 2 * SB);   // [2SB,4SB)
  unsigned short* y2t    = (unsigned short*)(ws);            // [0,2SB) (y dead)
  unsigned short* wqt  = (unsigned short*)(ws + 7 * SB);
  unsigned short* wkt  = wqt + 36864;
  unsigned short* wvt  = wkt + 36864;
  unsigned short* wpt  = wvt + 36864;
  unsigned short* wf1t = wpt + 36864;      // [768][192]
  unsigned short* wf2t = wf1t + 147456;    // [192][768]
  float* out = (float*)d_out;

  // 0) weight prep (bf16, [N][K])
  wtrans_kernel<<<dim3(6, 6), 256, 0, stream>>>(Wq_w, wqt, 192, 192);
  wtrans_kernel<<<dim3(6, 6), 256, 0, stream>>>(Wk_w, wkt, 192, 192);
  wtrans_kernel<<<dim3(6, 6), 256, 0, stream>>>(Wv_w, wvt, 192, 192);
  wtrans_kernel<<<dim3(6, 6), 256, 0, stream>>>(proj_w, wpt, 192, 192);
  wtrans_kernel<<<dim3(6, 24), 256, 0, stream>>>(fc1_w, wf1t, 192, 768);
  wtrans_kernel<<<dim3(24, 6), 256, 0, stream>>>(fc2_w, wf2t, 768, 192);
  // 1) LN1 -> bf16 CM
  ln_kernel<<<dim3(HW / 256), 256, 0, stream>>>(features, ln1_g, ln1_b, xnb);
  // 2) transpose -> bf16 TM
  trans_kernel<<<dim3(HW / 64, 6), 256, 0, stream>>>(xnb, xnt, CD);
  // 3) QKV MFMA (N=576, 3 segments) -> fp32 CM
  mgemm_kernel<0><<<dim3(9, HW / 128), 256, 0, stream>>>(xnt, wqt, wkt, wvt, Wq_b, Wk_b, Wv_b,
                                                         nullptr, qkv, 192, 192);
  // 4) LePE dwconv on v
  dwconv_kernel<float, float, false><<<dim3(3, 48, 192), 256, 0, stream>>>(v_, lepe_w, lepe_b, vl);
  // 5) window attention -> bf16 TM
  attn_kernel<<<dim3(6, 144), 1024, 0, stream>>>(q_, k_, v_, vl, pfa_v, pfa_i, rpi, rpb_t, attn_o);
  // 6) proj + shortcut -> fp32 CM x2
  mgemm_kernel<1><<<dim3(3, HW / 128), 256, 0, stream>>>(attn_o, wpt, wpt, wpt, proj_b, proj_b, proj_b,
                                                         features, x2, 192, 1 << 30);
  // 7) LN2 -> bf16 CM, transpose -> TM
  ln_kernel<<<dim3(HW / 256), 256, 0, stream>>>(x2, ln2_g, ln2_b, xn2b);
  trans_kernel<<<dim3(HW / 64, 6), 256, 0, stream>>>(xn2b, xn2t, CD);
  // 8) fc1 + GELU -> bf16 CM y
  mgemm_kernel<2><<<dim3(12, HW / 128), 256, 0, stream>>>(xn2t, wf1t, wf1t, wf1t, fc1_b, fc1_b, fc1_b,
                                                          nullptr, y_, 192, 1 << 30);
  // 9) y2 = y + gelu(dwconv(y)+b) -> bf16 CM
  dwconv_kernel<unsigned short, unsigned short, true><<<dim3(3, 48, 768), 256, 0, stream>>>(y_, dw_w, dw_b, y2_);
  // 10) transpose y2 -> bf16 TM
  trans_kernel<<<dim3(HW / 64, 24), 256, 0, stream>>>(y2_, y2t, HIDD);
  // 11) fc2 + x2 residual -> fp32 TM final output
  mgemm_kernel<3><<<dim3(3, HW / 128), 256, 0, stream>>>(y2t, wf2t, wf2t, wf2t, fc2_b, fc2_b, fc2_b,
                                                         x2, out, 768, 1 << 30);
}

// Round 3
// 800.670 us; speedup vs baseline: 1.6835x; 1.1740x over previous
//
#include <hip/hip_runtime.h>
#include <math.h>

#define HW 36864
#define CD 192
#define NH 6
#define HDIM 32
#define HIDD 768

typedef unsigned short u16;
typedef __attribute__((ext_vector_type(8))) short bf16x8;
typedef __attribute__((ext_vector_type(4))) float f32x4;

__device__ __forceinline__ float gelu_f(float x) {
  return 0.5f * x * (1.0f + erff(x * 0.70710678118654752f));
}
__device__ __forceinline__ u16 f2b(float f) {
  union { float f; unsigned u; } v; v.f = f;
  unsigned r = v.u + 0x7fff + ((v.u >> 16) & 1);   // RNE
  return (u16)(r >> 16);
}
__device__ __forceinline__ float b2f(u16 b) {
  union { unsigned u; float f; } v; v.u = ((unsigned)b) << 16;
  return v.f;
}
__device__ __forceinline__ float ldv(const float* p) { return *p; }
__device__ __forceinline__ float ldv(const u16* p) { return b2f(*p); }

// ---------- fused LayerNorm + transpose: fp32 CM in -> bf16 TM out ----------
__global__ __launch_bounds__(256)
void lnt_kernel(const float* __restrict__ in, const float* __restrict__ g,
                const float* __restrict__ b, u16* __restrict__ outTM)
{
  __shared__ float tile[64][193];
  __shared__ float red[64][8];
  __shared__ float2 stat2[64];
  __shared__ float gb[384];
  const int tid = threadIdx.x;
  const int part = tid >> 6, tk = tid & 63;
  const int tok = blockIdx.x * 64 + tk;
  if (tid < 192) { gb[tid] = g[tid]; gb[192 + tid] = b[tid]; }
  float s = 0.f, sq = 0.f;
  for (int c = part * 48; c < part * 48 + 48; ++c) {
    float v = in[(size_t)c * HW + tok];
    tile[tk][c] = v; s += v; sq += v * v;
  }
  red[tk][part] = s; red[tk][4 + part] = sq;
  __syncthreads();
  if (tid < 64) {
    float ss = red[tid][0] + red[tid][1] + red[tid][2] + red[tid][3];
    float qq = red[tid][4] + red[tid][5] + red[tid][6] + red[tid][7];
    float m = ss * (1.0f / CD);
    float var = fmaxf(qq * (1.0f / CD) - m * m, 0.f);
    stat2[tid] = make_float2(m, rsqrtf(var + 1e-5f));
  }
  __syncthreads();
  unsigned* op = (unsigned*)outTM + (size_t)blockIdx.x * 6144;
  #pragma unroll
  for (int r = 0; r < 24; ++r) {
    int idx = tid + r * 256;
    int tok2 = idx / 96, dc = idx - tok2 * 96;
    float2 st = stat2[tok2];
    int c = dc * 2;
    float v0 = (tile[tok2][c] - st.x) * st.y * gb[c] + gb[192 + c];
    float v1 = (tile[tok2][c + 1] - st.x) * st.y * gb[c + 1] + gb[192 + c + 1];
    op[idx] = (unsigned)f2b(v0) | ((unsigned)f2b(v1) << 16);
  }
}

// ---------- bf16 CM [C][HW] -> bf16 TM [HW][C] transpose (for y2, C=768) ----------
__global__ __launch_bounds__(256)
void trans_kernel(const u16* __restrict__ in, u16* __restrict__ out, int C)
{
  __shared__ u16 ls[64][34];
  const int m0 = blockIdx.x * 64, c0 = blockIdx.y * 32;
  const int t = threadIdx.x;
  #pragma unroll
  for (int r = 0; r < 4; ++r) {
    int idx = t + r * 256;
    int c = idx >> 5, dm = idx & 31;
    unsigned d = *(const unsigned*)(in + (size_t)(c0 + c) * HW + m0 + dm * 2);
    ls[dm * 2][c] = (u16)d;
    ls[dm * 2 + 1][c] = (u16)(d >> 16);
  }
  __syncthreads();
  #pragma unroll
  for (int r = 0; r < 4; ++r) {
    int idx = t + r * 256;
    int m = idx >> 4, dc = idx & 15;
    unsigned d = (unsigned)ls[m][dc * 2] | ((unsigned)ls[m][dc * 2 + 1] << 16);
    *(unsigned*)(out + (size_t)(m0 + m) * C + c0 + dc * 2) = d;
  }
}

// ---------- weight prep: fp32 [K][N] -> bf16 [N][K] ----------
__global__ __launch_bounds__(256)
void wtrans_kernel(const float* __restrict__ in, u16* __restrict__ out, int K, int N)
{
  __shared__ float ls[32][33];
  const int k0 = blockIdx.x * 32, n0 = blockIdx.y * 32;
  const int t = threadIdx.x;
  #pragma unroll
  for (int r = 0; r < 4; ++r) {
    int idx = t + r * 256;
    int k = idx >> 5, n = idx & 31;
    ls[k][n] = in[(size_t)(k0 + k) * N + n0 + n];
  }
  __syncthreads();
  #pragma unroll
  for (int r = 0; r < 4; ++r) {
    int idx = t + r * 256;
    int n = idx >> 5, k = idx & 31;
    out[(size_t)(n0 + n) * K + k0 + k] = f2b(ls[k][n]);
  }
}

// 4 square 192x192 weights in one launch
__global__ __launch_bounds__(256)
void wtrans4_kernel(const float* __restrict__ w0, const float* __restrict__ w1,
                    const float* __restrict__ w2, const float* __restrict__ w3,
                    u16* __restrict__ out)
{
  __shared__ float ls[32][33];
  const int z = blockIdx.z;
  const float* in = (z == 0) ? w0 : (z == 1 ? w1 : (z == 2 ? w2 : w3));
  u16* op = out + (size_t)z * CD * CD;
  const int k0 = blockIdx.x * 32, n0 = blockIdx.y * 32;
  const int t = threadIdx.x;
  #pragma unroll
  for (int r = 0; r < 4; ++r) {
    int idx = t + r * 256;
    int k = idx >> 5, n = idx & 31;
    ls[k][n] = in[(size_t)(k0 + k) * CD + n0 + n];
  }
  __syncthreads();
  #pragma unroll
  for (int r = 0; r < 4; ++r) {
    int idx = t + r * 256;
    int n = idx >> 5, k = idx & 31;
    op[(size_t)(n0 + n) * CD + k0 + k] = f2b(ls[k][n]);
  }
}

// ---------- bf16 MFMA GEMM: D[m][n] = A[m][:].Wt[n][:] + epilogue ----------
// MODE 0: QKV  -> bf16 CM out, +bias, q-segment scaled
// MODE 1: PROJ -> fp32 CM out, +bias +aux (fp32 CM)
// MODE 2: FC1  -> bf16 CM out, +bias, GELU
// MODE 3: FC2  -> fp32 TM out, +bias +aux (fp32 CM)
template<int MODE>
__global__ __launch_bounds__(256, 4)
void mgemm_kernel(const u16* __restrict__ A,
                  const u16* __restrict__ W0, const u16* __restrict__ W1, const u16* __restrict__ W2,
                  const float* __restrict__ b0, const float* __restrict__ b1, const float* __restrict__ b2,
                  const float* __restrict__ aux, void* __restrict__ outv,
                  int K, int segN)
{
  const int n0 = blockIdx.x * 64;
  const int m0 = blockIdx.y * 128;
  const int seg = n0 / segN;
  const u16* Wp = (seg == 0) ? W0 : (seg == 1 ? W1 : W2);
  const float* biasp = (seg == 0) ? b0 : (seg == 1 ? b1 : b2);
  const int nl0 = n0 - seg * segN;

  __shared__ u16 As[128 * 32];
  __shared__ u16 Bs[64 * 32];

  const int tid = threadIdx.x;
  const int lane = tid & 63, wave = tid >> 6;
  const int wm = (wave >> 1) * 64, wn = (wave & 1) * 32;
  const int fm = lane & 15, fq = lane >> 4;
  const int ar = tid >> 2, akq = tid & 3;

  f32x4 acc[4][2];
  #pragma unroll
  for (int i = 0; i < 4; ++i) { acc[i][0] = (f32x4)(0.f); acc[i][1] = (f32x4)(0.f); }

  uint4 rA0, rA1, rB, nA0, nA1, nB;
  rA0 = *(const uint4*)(A + (size_t)(m0 + ar) * K + akq * 8);
  rA1 = *(const uint4*)(A + (size_t)(m0 + ar + 64) * K + akq * 8);
  rB  = *(const uint4*)(Wp + (size_t)(nl0 + ar) * K + akq * 8);

  for (int k0 = 0; k0 < K; k0 += 32) {
    *(uint4*)(&As[ar * 32 + akq * 8]) = rA0;
    *(uint4*)(&As[(ar + 64) * 32 + akq * 8]) = rA1;
    *(uint4*)(&Bs[ar * 32 + akq * 8]) = rB;
    __syncthreads();
    const int kn = (k0 + 32 < K) ? k0 + 32 : k0;
    nA0 = *(const uint4*)(A + (size_t)(m0 + ar) * K + kn + akq * 8);
    nA1 = *(const uint4*)(A + (size_t)(m0 + ar + 64) * K + kn + akq * 8);
    nB  = *(const uint4*)(Wp + (size_t)(nl0 + ar) * K + kn + akq * 8);
    bf16x8 af[4], bf[2];
    #pragma unroll
    for (int mt = 0; mt < 4; ++mt)
      af[mt] = *(const bf16x8*)(&As[(wm + mt * 16 + fm) * 32 + fq * 8]);
    #pragma unroll
    for (int nt = 0; nt < 2; ++nt)
      bf[nt] = *(const bf16x8*)(&Bs[(wn + nt * 16 + fm) * 32 + fq * 8]);
    #pragma unroll
    for (int mt = 0; mt < 4; ++mt)
      #pragma unroll
      for (int nt = 0; nt < 2; ++nt)
        acc[mt][nt] = __builtin_amdgcn_mfma_f32_16x16x32_bf16(af[mt], bf[nt], acc[mt][nt], 0, 0, 0);
    __syncthreads();
    rA0 = nA0; rA1 = nA1; rB = nB;
  }

  #pragma unroll
  for (int nt = 0; nt < 2; ++nt) {
    const int n = n0 + wn + nt * 16 + fm;
    const float bia = biasp[nl0 + wn + nt * 16 + fm];
    #pragma unroll
    for (int mt = 0; mt < 4; ++mt) {
      const int mb = m0 + wm + mt * 16 + fq * 4;
      float o[4];
      #pragma unroll
      for (int r = 0; r < 4; ++r) o[r] = acc[mt][nt][r] + bia;
      if (MODE == 0) {
        const float sc = (seg == 0) ? 0.17677669529663689f : 1.0f;  // q pre-scaled by hd^-0.5
        u16 h0 = f2b(o[0] * sc), h1 = f2b(o[1] * sc), h2 = f2b(o[2] * sc), h3 = f2b(o[3] * sc);
        uint2 pk = make_uint2((unsigned)h0 | ((unsigned)h1 << 16), (unsigned)h2 | ((unsigned)h3 << 16));
        *(uint2*)((u16*)outv + (size_t)n * HW + mb) = pk;
      } else if (MODE == 1) {
        const float4 ax = *(const float4*)(aux + (size_t)n * HW + mb);
        *(float4*)((float*)outv + (size_t)n * HW + mb) =
            make_float4(o[0] + ax.x, o[1] + ax.y, o[2] + ax.z, o[3] + ax.w);
      } else if (MODE == 2) {
        u16 h0 = f2b(gelu_f(o[0])), h1 = f2b(gelu_f(o[1]));
        u16 h2 = f2b(gelu_f(o[2])), h3 = f2b(gelu_f(o[3]));
        uint2 pk = make_uint2((unsigned)h0 | ((unsigned)h1 << 16), (unsigned)h2 | ((unsigned)h3 << 16));
        *(uint2*)((u16*)outv + (size_t)n * HW + mb) = pk;
      } else {
        const float4 ax = *(const float4*)(aux + (size_t)n * HW + mb);
        float* op = (float*)outv;
        op[(size_t)(mb + 0) * CD + n] = o[0] + ax.x;
        op[(size_t)(mb + 1) * CD + n] = o[1] + ax.y;
        op[(size_t)(mb + 2) * CD + n] = o[2] + ax.z;
        op[(size_t)(mb + 3) * CD + n] = o[3] + ax.w;
      }
    }
  }
}

// ---------- depthwise 5x5 conv + bias + exact GELU (+optional residual) ----------
template<bool ADD>
__global__ __launch_bounds__(256)
void dwconv_kernel(const u16* __restrict__ in, const float* __restrict__ w,
                   const float* __restrict__ bias, u16* __restrict__ out)
{
  const int plane = blockIdx.z;
  const int bx = blockIdx.x * 64, by = blockIdx.y * 4;
  __shared__ float tile[8][68];
  __shared__ float ws[26];
  const int tid = threadIdx.x;
  if (tid < 26) ws[tid] = (tid < 25) ? w[plane * 25 + tid] : bias[plane];
  const u16* ip = in + (size_t)plane * HW;
  for (int e = tid; e < 544; e += 256) {
    int r = e / 68, cc = e - r * 68;
    int gy = by + r - 2, gx = bx + cc - 2;
    tile[r][cc] = (gy >= 0 && gy < 192 && gx >= 0 && gx < 192) ? b2f(ip[gy * 192 + gx]) : 0.f;
  }
  __syncthreads();
  const int tx = tid & 63, ty = tid >> 6;
  float acc = 0.f;
  #pragma unroll
  for (int dy = 0; dy < 5; ++dy)
    #pragma unroll
    for (int dx = 0; dx < 5; ++dx)
      acc = fmaf(tile[ty + dy][tx + dx], ws[dy * 5 + dx], acc);
  float v = gelu_f(acc + ws[25]);
  if (ADD) v += tile[ty + 2][tx + 2];
  out[(size_t)plane * HW + (by + ty) * 192 + bx + tx] = f2b(v);
}

// ---------- fused window attention v3: 512 thr, 2 blocks/CU, MFMA scores ----------
__global__ __launch_bounds__(512, 4)
void attn_kernel(const u16* __restrict__ qg, const u16* __restrict__ kg,
                 const u16* __restrict__ vg, const u16* __restrict__ vlg,
                 const float* __restrict__ pfa_v, const int* __restrict__ pfa_i,
                 const int* __restrict__ rpi, const float* __restrict__ rpb_t,
                 u16* __restrict__ attn_out)
{
  const int h = blockIdx.x;
  const int win = blockIdx.y;
  const int wy = (win / 12) * 16;
  const int wx = (win - (win / 12) * 12) * 16;
  const size_t hb = (size_t)h * HDIM * HW;

  __shared__ u16 kT[256][40];       // [j][d] bf16, rows 80B (b128-aligned)  20480 B
  __shared__ u16 vT[32][258];       // [d][j] bf16                           16512 B
  __shared__ float Sb[32][264];     //                                       33792 B
  __shared__ u16 qT[32][40];        // [i][d] per pass                        2560 B
  __shared__ float rpb_h[964];      //                                        3856 B
  __shared__ float2 selbuf[8][64];  //                                        4096 B

  const int tid = threadIdx.x;
  const int lane = tid & 63, wave = tid >> 6;

  for (int r = tid; r < 961; r += 512) rpb_h[r] = rpb_t[r * 6 + h];

  #pragma unroll
  for (int r = 0; r < 8; ++r) {
    int idx = tid + r * 512;
    int d = idx >> 7, jp = idx & 127, j = jp * 2;
    int pg = (wy + (j >> 4)) * 192 + (wx + (j & 15));
    ushort2 kv = *(const ushort2*)(kg + hb + (size_t)d * HW + pg);
    kT[j][d] = kv.x; kT[j + 1][d] = kv.y;
    *(ushort2*)&vT[d][j] = *(const ushort2*)(vg + hb + (size_t)d * HW + pg);
  }
  __syncthreads();

  const size_t wb = ((size_t)win * NH + h) * 256;

  for (int pass = 0; pass < 8; ++pass) {
    // stage qT (q already scaled by hd^-0.5 in QKV epilogue)
    {
      int d = tid >> 4, ip = tid & 15, i = pass * 32 + ip * 2;
      int pg = (wy + (i >> 4)) * 192 + (wx + (i & 15));
      ushort2 qv = *(const ushort2*)(qg + hb + (size_t)d * HW + pg);
      qT[ip * 2][d] = qv.x; qT[ip * 2 + 1][d] = qv.y;
    }
    __syncthreads();
    // scores via MFMA: 2x16 tiles of 16x16, 4 per wave
    {
      const int it = wave & 1;
      bf16x8 aq = *(const bf16x8*)&qT[it * 16 + (lane & 15)][(lane >> 4) * 8];
      #pragma unroll
      for (int t = 0; t < 4; ++t) {
        int j0 = ((wave >> 1) * 4 + t) * 16;
        bf16x8 bk = *(const bf16x8*)&kT[j0 + (lane & 15)][(lane >> 4) * 8];
        f32x4 c = __builtin_amdgcn_mfma_f32_16x16x32_bf16(aq, bk, (f32x4)(0.f), 0, 0, 0);
        const int col = j0 + (lane & 15), rowb = it * 16 + (lane >> 4) * 4;
        Sb[rowb + 0][col] = c[0]; Sb[rowb + 1][col] = c[1];
        Sb[rowb + 2][col] = c[2]; Sb[rowb + 3][col] = c[3];
      }
    }
    __syncthreads();
    // per-query: 4 queries per wave
    int pj1[4], pj2[4]; float pv1[4], pv2[4], rb1[4], rb2[4];
    #pragma unroll
    for (int u = 0; u < 4; ++u) {
      const int i = pass * 32 + u * 8 + wave;
      const size_t base = (wb + (size_t)i) * 128;
      pj1[u] = pfa_i[base + lane];  pj2[u] = pfa_i[base + 64 + lane];
      pv1[u] = pfa_v[base + lane];  pv2[u] = pfa_v[base + 64 + lane];
    }
    #pragma unroll
    for (int u = 0; u < 4; ++u) {
      const int i = pass * 32 + u * 8 + wave;
      rb1[u] = rpb_h[rpi[i * 256 + pj1[u]]];
      rb2[u] = rpb_h[rpi[i * 256 + pj2[u]]];
    }
    #pragma unroll
    for (int u = 0; u < 4; ++u) {
      const int iq = u * 8 + wave;
      const int i  = pass * 32 + iq;
      const int j1 = pj1[u], j2 = pj2[u];
      float s1 = Sb[iq][j1] + rb1[u];
      float s2 = Sb[iq][j2] + rb2[u];
      float mx = fmaxf(s1, s2);
      #pragma unroll
      for (int o = 32; o > 0; o >>= 1) mx = fmaxf(mx, __shfl_xor(mx, o));
      float e1 = expf(s1 - mx), e2 = expf(s2 - mx);
      float sA = e1 + e2;
      float sB = e1 * pv1[u] + e2 * pv2[u];
      #pragma unroll
      for (int o = 32; o > 0; o >>= 1) { sA += __shfl_xor(sA, o); sB += __shfl_xor(sB, o); }
      const float rs = 1.0f / sA;
      float a1 = e1 * rs * pv1[u];
      float a2 = e2 * rs * pv2[u];
      const float rden = 1.0f / (sB * rs + 1e-10f);
      a1 = (a1 + 1e-10f) * rden;
      a2 = (a2 + 1e-10f) * rden;
      // exact top-64 threshold via radix select with early exit
      const unsigned ub1 = __float_as_uint(a1), ub2 = __float_as_uint(a2);
      unsigned thr = 0u;
      for (int bit = 30; bit >= 0; --bit) {
        unsigned cand = thr | (1u << bit);
        int cnt = (int)__popcll(__ballot(ub1 >= cand)) + (int)__popcll(__ballot(ub2 >= cand));
        if (cnt >= 64) { thr = cand; if (cnt == 64) break; }
      }
      const unsigned long long lmlt = (1ull << lane) - 1ull;
      const bool gt1 = ub1 > thr, gt2 = ub2 > thr;
      const bool eq1 = ub1 == thr, eq2 = ub2 == thr;
      const unsigned long long meq1 = __ballot(eq1), meq2 = __ballot(eq2);
      const int need = 64 - (int)__popcll(__ballot(gt1)) - (int)__popcll(__ballot(gt2));
      const bool sel1 = gt1 || (eq1 && (int)__popcll(meq1 & lmlt) < need);
      const bool sel2 = gt2 || (eq2 && ((int)__popcll(meq1) + (int)__popcll(meq2 & lmlt)) < need);
      const unsigned long long ms1 = __ballot(sel1), ms2 = __ballot(sel2);
      const int pos1 = (int)__popcll(ms1 & lmlt);
      const int pos2 = (int)__popcll(ms1) + (int)__popcll(ms2 & lmlt);
      if (sel1) selbuf[wave][pos1] = make_float2(a1, __int_as_float(j1));
      if (sel2) selbuf[wave][pos2] = make_float2(a2, __int_as_float(j2));
      // sparse AmV, batched selbuf reads
      const int d = lane & 31, half = lane >> 5;
      float acc = 0.f;
      #pragma unroll
      for (int c = 0; c < 4; ++c) {
        float2 sv[8];
        #pragma unroll
        for (int q4 = 0; q4 < 4; ++q4)
          *(float4*)&sv[q4 * 2] = *(const float4*)&selbuf[wave][half * 32 + c * 8 + q4 * 2];
        #pragma unroll
        for (int s = 0; s < 8; ++s)
          acc = fmaf(sv[s].x, b2f(vT[d][__float_as_int(sv[s].y)]), acc);
      }
      acc += __shfl_xor(acc, 32);
      const int pg = (wy + (i >> 4)) * 192 + (wx + (i & 15));
      if (lane < 32) {
        float o = acc + b2f(vlg[hb + (size_t)d * HW + pg]);
        attn_out[(size_t)pg * CD + h * HDIM + d] = f2b(o);
      }
    }
    __syncthreads();
  }
}

// ---------- launch ----------
extern "C" void kernel_launch(void* const* d_in, const int* in_sizes, int n_in,
                              void* d_out, int out_size, void* d_ws, size_t ws_size,
                              hipStream_t stream)
{
  (void)in_sizes; (void)n_in; (void)out_size; (void)ws_size;
  const float* features = (const float*)d_in[0];
  const float* pfa_v    = (const float*)d_in[1];
  const int*   pfa_i    = (const int*)d_in[2];
  const int*   rpi      = (const int*)d_in[3];
  const float* ln1_g    = (const float*)d_in[4];
  const float* ln1_b    = (const float*)d_in[5];
  const float* Wq_w     = (const float*)d_in[6];
  const float* Wq_b     = (const float*)d_in[7];
  const float* Wk_w     = (const float*)d_in[8];
  const float* Wk_b     = (const float*)d_in[9];
  const float* Wv_w     = (const float*)d_in[10];
  const float* Wv_b     = (const float*)d_in[11];
  const float* lepe_w   = (const float*)d_in[12];
  const float* lepe_b   = (const float*)d_in[13];
  const float* rpb_t    = (const float*)d_in[14];
  const float* proj_w   = (const float*)d_in[15];
  const float* proj_b   = (const float*)d_in[16];
  const float* ln2_g    = (const float*)d_in[17];
  const float* ln2_b    = (const float*)d_in[18];
  const float* fc1_w    = (const float*)d_in[19];
  const float* fc1_b    = (const float*)d_in[20];
  const float* dw_w     = (const float*)d_in[21];
  const float* dw_b     = (const float*)d_in[22];
  const float* fc2_w    = (const float*)d_in[23];
  const float* fc2_b    = (const float*)d_in[24];

  char* ws = (char*)d_ws;
  const size_t S  = (size_t)HW * CD;
  const size_t SB = S * 4;
  u16*   xnt    = (u16*)(ws);                         // [0, 0.5SB) bf16 TM
  u16*   qkvb   = (u16*)(ws + SB / 2);                // [0.5SB, 2SB) bf16 CM (q scaled, k, v)
  u16*   q_ = qkvb; u16* k_ = qkvb + S; u16* v_ = qkvb + 2 * S;
  u16*   vl     = (u16*)(ws + 2 * SB);                // [2SB, 2.5SB)
  u16*   attn_o = (u16*)(ws + 2 * SB + SB / 2);       // [2.5SB, 3SB) bf16 TM
  float* x2     = (float*)(ws + 3 * SB);              // [3SB, 4SB) fp32 CM, live to end
  u16*   xn2t   = (u16*)(ws + 4 * SB);                // [4SB, 4.5SB)
  u16*   y_     = (u16*)(ws + 4 * SB + SB / 2);       // [4.5SB, 6.5SB) bf16 CM 768xHW
  u16*   y2_    = (u16*)(ws + 6 * SB + SB / 2);       // [6.5SB, 8.5SB)
  u16*   y2t    = (u16*)(ws);                         // [0, 2SB) reuse (xnt/qkvb dead)
  u16*   wqt  = (u16*)(ws + 8 * SB + SB / 2);
  u16*   wkt  = wqt + 36864;
  u16*   wvt  = wkt + 36864;
  u16*   wpt  = wvt + 36864;
  u16*   wf1t = wpt + 36864;      // [768][192]
  u16*   wf2t = wf1t + 147456;    // [192][768]
  float* out = (float*)d_out;

  // 0) weight prep
  wtrans4_kernel<<<dim3(6, 6, 4), 256, 0, stream>>>(Wq_w, Wk_w, Wv_w, proj_w, wqt);
  wtrans_kernel<<<dim3(6, 24), 256, 0, stream>>>(fc1_w, wf1t, 192, 768);
  wtrans_kernel<<<dim3(24, 6), 256, 0, stream>>>(fc2_w, wf2t, 768, 192);
  // 1) LN1 fused transpose -> bf16 TM
  lnt_kernel<<<dim3(HW / 64), 256, 0, stream>>>(features, ln1_g, ln1_b, xnt);
  // 2) QKV MFMA -> bf16 CM (q scaled)
  mgemm_kernel<0><<<dim3(9, HW / 128), 256, 0, stream>>>(xnt, wqt, wkt, wvt, Wq_b, Wk_b, Wv_b,
                                                         nullptr, qkvb, 192, 192);
  // 3) LePE dwconv on v (bf16)
  dwconv_kernel<false><<<dim3(3, 48, 192), 256, 0, stream>>>(v_, lepe_w, lepe_b, vl);
  // 4) window attention -> bf16 TM
  attn_kernel<<<dim3(6, 144), 512, 0, stream>>>(q_, k_, v_, vl, pfa_v, pfa_i, rpi, rpb_t, attn_o);
  // 5) proj + shortcut -> fp32 CM x2
  mgemm_kernel<1><<<dim3(3, HW / 128), 256, 0, stream>>>(attn_o, wpt, wpt, wpt, proj_b, proj_b, proj_b,
                                                         features, x2, 192, 1 << 30);
  // 6) LN2 fused transpose -> bf16 TM
  lnt_kernel<<<dim3(HW / 64), 256, 0, stream>>>(x2, ln2_g, ln2_b, xn2t);
  // 7) fc1 + GELU -> bf16 CM y
  mgemm_kernel<2><<<dim3(12, HW / 128), 256, 0, stream>>>(xn2t, wf1t, wf1t, wf1t, fc1_b, fc1_b, fc1_b,
                                                          nullptr, y_, 192, 1 << 30);
  // 8) y2 = y + gelu(dwconv(y)+b) -> bf16 CM
  dwconv_kernel<true><<<dim3(3, 48, 768), 256, 0, stream>>>(y_, dw_w, dw_b, y2_);
  // 9) transpose y2 -> bf16 TM
  trans_kernel<<<dim3(HW / 64, 24), 256, 0, stream>>>(y2_, y2t, HIDD);
  // 10) fc2 + x2 residual -> fp32 TM final output
  mgemm_kernel<3><<<dim3(3, HW / 128), 256, 0, stream>>>(y2t, wf2t, wf2t, wf2t, fc2_b, fc2_b, fc2_b,
                                                         x2, out, 768, 1 << 30);
}